// Round 3
// baseline (237.086 us; speedup 1.0000x reference)
//
#include <hip/hip_runtime.h>

#define BLOCK 256
#define GRID 2048
#define UNROLL 4

__global__ __launch_bounds__(BLOCK) void loss_partial_kernel(
    const float* __restrict__ pred,   // (N,2) row-major
    const int* __restrict__ target,   // (N,)
    float* __restrict__ partials,     // (GRID,)
    int n4)                           // N/4 groups of 4 rows
{
    const float4* __restrict__ pred4 = reinterpret_cast<const float4*>(pred);
    const int4* __restrict__ tgt4 = reinterpret_cast<const int4*>(target);

    const int stride = GRID * BLOCK;
    int i = blockIdx.x * BLOCK + threadIdx.x;
    float acc = 0.0f;

    // Main loop: UNROLL independent 4-row batches, all 3*UNROLL loads issued
    // before any consumption -> ~192 B in flight per lane for latency hiding.
    for (; i + (UNROLL - 1) * stride < n4; i += UNROLL * stride) {
        float4 pa[UNROLL], pb[UNROLL];
        int4 t[UNROLL];
#pragma unroll
        for (int u = 0; u < UNROLL; ++u) {
            const int j = i + u * stride;
            pa[u] = pred4[2 * j];
            pb[u] = pred4[2 * j + 1];
            t[u]  = tgt4[j];
        }
#pragma unroll
        for (int u = 0; u < UNROLL; ++u) {
            float p0[4] = {pa[u].x, pa[u].z, pb[u].x, pb[u].z};
            float p1[4] = {pa[u].y, pa[u].w, pb[u].y, pb[u].w};
            int tt[4]   = {t[u].x, t[u].y, t[u].z, t[u].w};
#pragma unroll
            for (int k = 0; k < 4; ++k) {
                bool z = (tt[k] == 0);
                float a = z ? p0[k] : p1[k];   // prob of correct class
                float b = z ? p1[k] : p0[k];   // prob of wrong class
                float d = 1.0f - a;
                float s = fmaf(d, d, b * b);
                s += (a < b) ? 2.0f : 0.0f;
                acc += s;
            }
        }
    }

    // Tail (does not execute for N=16777216 with GRID*BLOCK=524288, kept for safety)
    for (; i < n4; i += stride) {
        float4 pa = pred4[2 * i];
        float4 pb = pred4[2 * i + 1];
        int4 t = tgt4[i];
        float p0[4] = {pa.x, pa.z, pb.x, pb.z};
        float p1[4] = {pa.y, pa.w, pb.y, pb.w};
        int tt[4]   = {t.x, t.y, t.z, t.w};
#pragma unroll
        for (int k = 0; k < 4; ++k) {
            bool z = (tt[k] == 0);
            float a = z ? p0[k] : p1[k];
            float b = z ? p1[k] : p0[k];
            float d = 1.0f - a;
            float s = fmaf(d, d, b * b);
            s += (a < b) ? 2.0f : 0.0f;
            acc += s;
        }
    }

    // wave64 butterfly reduce
#pragma unroll
    for (int off = 32; off > 0; off >>= 1)
        acc += __shfl_down(acc, off, 64);

    __shared__ float wsum[BLOCK / 64];
    const int lane = threadIdx.x & 63;
    const int wid = threadIdx.x >> 6;
    if (lane == 0) wsum[wid] = acc;
    __syncthreads();
    if (threadIdx.x == 0) {
        float s = 0.0f;
#pragma unroll
        for (int w = 0; w < BLOCK / 64; ++w) s += wsum[w];
        partials[blockIdx.x] = s;
    }
}

__global__ __launch_bounds__(BLOCK) void loss_final_kernel(
    const float* __restrict__ partials, float* __restrict__ out,
    int nparts, float inv_n)
{
    float acc = 0.0f;
    for (int i = threadIdx.x; i < nparts; i += BLOCK)
        acc += partials[i];

#pragma unroll
    for (int off = 32; off > 0; off >>= 1)
        acc += __shfl_down(acc, off, 64);

    __shared__ float wsum[BLOCK / 64];
    const int lane = threadIdx.x & 63;
    const int wid = threadIdx.x >> 6;
    if (lane == 0) wsum[wid] = acc;
    __syncthreads();
    if (threadIdx.x == 0) {
        float s = 0.0f;
#pragma unroll
        for (int w = 0; w < BLOCK / 64; ++w) s += wsum[w];
        out[0] = s * inv_n;
    }
}

extern "C" void kernel_launch(void* const* d_in, const int* in_sizes, int n_in,
                              void* d_out, int out_size, void* d_ws, size_t ws_size,
                              hipStream_t stream) {
    const float* pred = (const float*)d_in[0];
    const int* target = (const int*)d_in[1];
    float* out = (float*)d_out;
    float* partials = (float*)d_ws;

    // pred is (N,2) -> in_sizes[0] == 2N; target is (N,) -> in_sizes[1] == N.
    int n = in_sizes[1];
    if (n * 2 != in_sizes[0]) n = in_sizes[0] / 2;   // defensive fallback
    const int n4 = n / 4;                            // N = 16777216, multiple of 4

    loss_partial_kernel<<<GRID, BLOCK, 0, stream>>>(pred, target, partials, n4);
    loss_final_kernel<<<1, BLOCK, 0, stream>>>(partials, out, GRID, 1.0f / (float)n);
}

// Round 4
// 234.975 us; speedup vs baseline: 1.0090x; 1.0090x over previous
//
#include <hip/hip_runtime.h>

#define BLOCK 256
#define GRID 2048
#define UNROLL 4

// Layout: one float4 = probs of 2 consecutive rows (p0,p1,p0',p1'),
// one int2 = targets of those same 2 rows, at the SAME linear index.
// => every load instruction is dense stride-1 across the wave, and each
// block streams one contiguous 96 KB region (DRAM/row-buffer friendly).
__global__ __launch_bounds__(BLOCK) void loss_partial_kernel(
    const float4* __restrict__ pred4,  // N/2 elements
    const int2*  __restrict__ tgt2,    // N/2 elements
    float* __restrict__ partials,      // GRID
    int npairs)                        // N/2
{
    const int ppb  = (npairs + GRID - 1) / GRID;   // pairs per block (4096)
    const int base = blockIdx.x * ppb;
    const int end  = min(base + ppb, npairs);

    float acc = 0.0f;
    int k = base + threadIdx.x;

    for (; k + (UNROLL - 1) * BLOCK < end; k += UNROLL * BLOCK) {
        float4 p[UNROLL];
        int2   t[UNROLL];
#pragma unroll
        for (int u = 0; u < UNROLL; ++u) p[u] = pred4[k + u * BLOCK];
#pragma unroll
        for (int u = 0; u < UNROLL; ++u) t[u] = tgt2[k + u * BLOCK];
#pragma unroll
        for (int u = 0; u < UNROLL; ++u) {
            {   // row 0 of the pair: probs (x,y), target t.x
                bool z = (t[u].x == 0);
                float a = z ? p[u].x : p[u].y;
                float b = z ? p[u].y : p[u].x;
                float d = 1.0f - a;
                float s = fmaf(d, d, b * b);
                acc += s + ((a < b) ? 2.0f : 0.0f);
            }
            {   // row 1 of the pair: probs (z,w), target t.y
                bool z = (t[u].y == 0);
                float a = z ? p[u].z : p[u].w;
                float b = z ? p[u].w : p[u].z;
                float d = 1.0f - a;
                float s = fmaf(d, d, b * b);
                acc += s + ((a < b) ? 2.0f : 0.0f);
            }
        }
    }
    // tail (not taken for N=16777216: 4096 pairs/block, 16 exact steps)
    for (; k < end; k += BLOCK) {
        float4 p = pred4[k];
        int2   t = tgt2[k];
        {
            bool z = (t.x == 0);
            float a = z ? p.x : p.y;
            float b = z ? p.y : p.x;
            float d = 1.0f - a;
            acc += fmaf(d, d, b * b) + ((a < b) ? 2.0f : 0.0f);
        }
        {
            bool z = (t.y == 0);
            float a = z ? p.z : p.w;
            float b = z ? p.w : p.z;
            float d = 1.0f - a;
            acc += fmaf(d, d, b * b) + ((a < b) ? 2.0f : 0.0f);
        }
    }

    // wave64 butterfly reduce
#pragma unroll
    for (int off = 32; off > 0; off >>= 1)
        acc += __shfl_down(acc, off, 64);

    __shared__ float wsum[BLOCK / 64];
    const int lane = threadIdx.x & 63;
    const int wid  = threadIdx.x >> 6;
    if (lane == 0) wsum[wid] = acc;
    __syncthreads();
    if (threadIdx.x == 0) {
        float s = 0.0f;
#pragma unroll
        for (int w = 0; w < BLOCK / 64; ++w) s += wsum[w];
        partials[blockIdx.x] = s;
    }
}

__global__ __launch_bounds__(BLOCK) void loss_final_kernel(
    const float* __restrict__ partials, float* __restrict__ out,
    int nparts, float inv_n)
{
    float acc = 0.0f;
    for (int i = threadIdx.x; i < nparts; i += BLOCK)
        acc += partials[i];

#pragma unroll
    for (int off = 32; off > 0; off >>= 1)
        acc += __shfl_down(acc, off, 64);

    __shared__ float wsum[BLOCK / 64];
    const int lane = threadIdx.x & 63;
    const int wid  = threadIdx.x >> 6;
    if (lane == 0) wsum[wid] = acc;
    __syncthreads();
    if (threadIdx.x == 0) {
        float s = 0.0f;
#pragma unroll
        for (int w = 0; w < BLOCK / 64; ++w) s += wsum[w];
        out[0] = s * inv_n;
    }
}

extern "C" void kernel_launch(void* const* d_in, const int* in_sizes, int n_in,
                              void* d_out, int out_size, void* d_ws, size_t ws_size,
                              hipStream_t stream) {
    const float* pred = (const float*)d_in[0];
    const int* target = (const int*)d_in[1];
    float* out = (float*)d_out;
    float* partials = (float*)d_ws;

    int n = in_sizes[1];
    if (n * 2 != in_sizes[0]) n = in_sizes[0] / 2;   // defensive fallback
    const int npairs = n / 2;                        // N even (16777216)

    loss_partial_kernel<<<GRID, BLOCK, 0, stream>>>(
        (const float4*)pred, (const int2*)target, partials, npairs);
    loss_final_kernel<<<1, BLOCK, 0, stream>>>(partials, out, GRID, 1.0f / (float)n);
}